// Round 11
// baseline (6186.652 us; speedup 1.0000x reference)
//
#include <hip/hip_runtime.h>
#include <math.h>

#define BB 2048
#define TT 512
#define NFEAT 25
#define UNITS 300
#define RPB 16
#define NBLK (BB/RPB)    // 128
#define NT 512
#define NKS 11           // K-steps (352/32): ks0=gates, ks1-10=h
#define NTIL 80          // N'-tiles (1280/16), cols >=1200 pad
#define TPW 10           // tiles per wave (80/8 waves)
#define AROW 360         // Abf row stride (shorts); cols: 0-23 g, 24 comb, 32..331 h
#define GROW 72
#define WREG (NKS*TPW*512)   // per-wave B region

#define OFF_B  0
#define SZ_B   (NTIL*NKS*512)        // 450560
#define OFF_M1 (OFF_B + SZ_B)
#define SZ_M1  (4*2*512)
#define OFF_M2 (OFF_M1 + SZ_M1)
#define SZ_M2  (2*2*512)
#define OFF_H  (OFF_M2 + SZ_M2)
#define SZ_H   (2*NKS*512)
#define SW_SZ  (SZ_M1 + SZ_M2 + SZ_H)
#define SWM1   0
#define SWM2   (SZ_M1)
#define SWH    (SZ_M1 + SZ_M2)

typedef __attribute__((ext_vector_type(4))) float f32x4;
typedef __attribute__((ext_vector_type(8))) short bf16x8;

static __device__ __forceinline__ unsigned short f2bf(float f) {
    union { float f; unsigned u; } x; x.f = f;
    unsigned r = (x.u + 0x7fffu + ((x.u >> 16) & 1u)) >> 16;
    return (unsigned short)r;
}
static __device__ __forceinline__ float ftanh(float v) {
    float e = __builtin_amdgcn_exp2f(v * 2.8853900817779268f);
    return 1.f - 2.f * __builtin_amdgcn_rcpf(e + 1.f);
}

// big-GEMM B: [wave][ks][tile][512]; A-row map: k<25 -> wk[k], 32<=k<332 -> wr[k-32], else 0
// gate-interleaved z columns col' = 4*u + gate
__global__ __launch_bounds__(256) void conv_big(
    const float* __restrict__ wk, const float* __restrict__ wr,
    unsigned short* __restrict__ dst)
{
    int idx = blockIdx.x * 256 + threadIdx.x;
    if (idx >= SZ_B) return;
    int j = idx & 7, n = (idx >> 3) & 15, kg = (idx >> 7) & 3, qq = idx >> 9;
    int i = qq % TPW, ks = (qq / TPW) % NKS, w = qq / (TPW * NKS);
    int nt = w + 8 * i;
    int k = ks * 32 + kg * 8 + j, c = nt * 16 + n;
    float v = 0.f;
    if (c < 1200) {
        int oc = (c & 3) * 300 + (c >> 2);
        if (k < 25)                  v = wk[k * 1200 + oc];
        else if (k >= 32 && k < 332) v = wr[(k - 32) * 1200 + oc];
    }
    dst[OFF_B + idx] = f2bf(v);
}

__global__ __launch_bounds__(256) void conv_gen(
    const float* __restrict__ W, unsigned short* __restrict__ dst,
    int K, int N, int nks, int total)
{
    int idx = blockIdx.x * 256 + threadIdx.x;
    if (idx >= total) return;
    int j = idx & 7, n = (idx >> 3) & 15, kg = (idx >> 7) & 3, qq = idx >> 9;
    int ks = qq % nks, nt = qq / nks;
    int k = ks * 32 + kg * 8 + j, col = nt * 16 + n;
    float v = (k < K && col < N) ? W[k * N + col] : 0.f;
    dst[idx] = f2bf(v);
}

// heads B with K'=352, h at k=32..331 (u = k-32); ks0 all zero (skipped in kernel)
__global__ __launch_bounds__(256) void conv_heads(
    const float* __restrict__ wa, const float* __restrict__ wm,
    const float* __restrict__ wsg, unsigned short* __restrict__ dst)
{
    int idx = blockIdx.x * 256 + threadIdx.x;
    if (idx >= SZ_H) return;
    int j = idx & 7, n = (idx >> 3) & 15, kg = (idx >> 7) & 3, qq = idx >> 9;
    int ks = qq % NKS, nt = qq / NKS;
    int k = ks * 32 + kg * 8 + j, col = nt * 16 + n;
    float v = 0.f;
    if (k >= 32 && k < 332 && col < 24) {
        int u = k - 32, h = col >> 3, m = col & 7;
        const float* W = (h == 0) ? wa : (h == 1) ? wm : wsg;
        v = W[u * 8 + m];
    }
    dst[OFF_H + idx] = f2bf(v);
}

#define MFMA __builtin_amdgcn_mfma_f32_16x16x32_bf16

// h-part GEMM chunk: ks in [K0,K1), reading A from Abf[BUF], sequential B stream
#define HPART(BUF, K0, K1) do {                                               \
    const unsigned short* bp_ = bwave + (K0) * (TPW * 512);                   \
    _Pragma("unroll 1")                                                       \
    for (int ks = (K0); ks < (K1); ++ks) {                                    \
        bf16x8 aA_ = *(const bf16x8*)&Abf[BUF][arow][ks * 32 + akg * 8];      \
        bf16x8 bb_[TPW];                                                      \
        _Pragma("unroll")                                                     \
        for (int i = 0; i < TPW; ++i)                                         \
            bb_[i] = *(const bf16x8*)(bp_ + i * 512);                         \
        _Pragma("unroll")                                                     \
        for (int i = 0; i < TPW; ++i)                                         \
            acc[i] = MFMA(aA_, bb_[i], acc[i], 0, 0, 0);                      \
        bp_ += TPW * 512;                                                     \
    }                                                                         \
} while (0)

__global__ __launch_bounds__(NT, 2)
void dilstm(
    const float* __restrict__ x,
    const unsigned short* __restrict__ wf,
    const float* __restrict__ bz,
    const float* __restrict__ b1v,
    const float* __restrict__ b2v,
    const float* __restrict__ ba,
    const float* __restrict__ bm,
    const float* __restrict__ bs,
    float* __restrict__ out)
{
    __shared__ unsigned short Abf[2][RPB][AROW];
    __shared__ unsigned short Gbf[RPB][GROW];
    __shared__ unsigned short G1b[RPB][GROW];
    __shared__ float Sc[RPB][24];
    __shared__ float BzS[1280];
    __shared__ unsigned short SW[SW_SZ];

    const int t = threadIdx.x;
    const int lane = t & 63, wv = t >> 6;
    const int arow = lane & 15, akg = lane >> 4;
    const int crow0 = akg * 4;
    const int q4 = lane & 3, du = (lane >> 2) & 3;
    const int row0 = blockIdx.x * RPB;

    for (int i = t; i < 2 * RPB * AROW; i += NT) ((unsigned short*)Abf)[i] = 0;
    for (int i = t; i < RPB * GROW; i += NT) { ((unsigned short*)Gbf)[i] = 0; ((unsigned short*)G1b)[i] = 0; }
    for (int i = t; i < SW_SZ; i += NT) SW[i] = wf[OFF_M1 + i];
    for (int i = t; i < 1280; i += NT)
        BzS[i] = (i < 1200) ? bz[(i & 3) * 300 + (i >> 2)] : 0.f;

    float m1bias = 0.f, m2bias = 0.f, hbias = 0.f;
    {
        int c1 = wv * 16 + arow;
        if (wv < 4 && c1 < 50) m1bias = b1v[c1];
        if (wv < 2 && c1 < 24) {
            m2bias = b2v[c1];
            hbias = (c1 < 8) ? ba[c1] : (c1 < 16) ? bm[c1 - 8] : bs[c1 - 16];
        }
    }

    float creg[TPW];
    #pragma unroll
    for (int i = 0; i < TPW; ++i) creg[i] = 0.f;

    f32x4 acc[TPW];
    #pragma unroll
    for (int i = 0; i < TPW; ++i) acc[i] = (f32x4){0.f, 0.f, 0.f, 0.f};

    const unsigned short* bwave = wf + OFF_B + (size_t)wv * WREG + (lane << 3);

    const int rA = t / 25, eA = t - (t / 25) * 25;
    float combreg = 0.f, xreg = 0.f;
    if (t < RPB * NFEAT) xreg = x[((size_t)(row0 + rA) * TT) * NFEAT + eA];
    __syncthreads();

    // initial gate-input build (prev = 0); acc = hpart(0) = 0 since h(-1)=0
    if (t < RPB * NFEAT) {
        if (eA < 24) {
            Gbf[rA][eA] = f2bf(xreg);
        } else {
            float comb = xreg;
            combreg = comb;
            float denom = fmaxf(comb, 1e-8f);
            Gbf[rA][24] = f2bf(xreg / denom);
            Abf[0][rA][24] = f2bf(comb);
        }
    }
    __syncthreads();

    for (int ts = 0; ts < TT; ++ts) {
        const int p = ts & 1;

        // ---- P1: MLP1 (wv<4) || hpart(ts) ks6-8 ----
        if (wv < 4) {
            bf16x8 a0 = *(const bf16x8*)&Gbf[arow][akg * 8];
            bf16x8 a1 = *(const bf16x8*)&Gbf[arow][32 + akg * 8];
            bf16x8 b0 = *(const bf16x8*)&SW[SWM1 + (wv * 2 + 0) * 512 + (lane << 3)];
            bf16x8 b1 = *(const bf16x8*)&SW[SWM1 + (wv * 2 + 1) * 512 + (lane << 3)];
            f32x4 acc1 = {0.f, 0.f, 0.f, 0.f};
            acc1 = MFMA(a0, b0, acc1, 0, 0, 0);
            acc1 = MFMA(a1, b1, acc1, 0, 0, 0);
            int col = wv * 16 + arow;
            if (col < 50) {
                #pragma unroll
                for (int rg = 0; rg < 4; ++rg)
                    G1b[crow0 + rg][col] = f2bf(fmaxf(acc1[rg] + m1bias, 0.f));
            }
        }
        HPART(p, 6, 9);
        __syncthreads();

        // ---- P2: MLP2 (wv<2) || hpart(ts) ks9-10 ----
        if (wv < 2) {
            bf16x8 a0 = *(const bf16x8*)&G1b[arow][akg * 8];
            bf16x8 a1 = *(const bf16x8*)&G1b[arow][32 + akg * 8];
            bf16x8 b0 = *(const bf16x8*)&SW[SWM2 + (wv * 2 + 0) * 512 + (lane << 3)];
            bf16x8 b1 = *(const bf16x8*)&SW[SWM2 + (wv * 2 + 1) * 512 + (lane << 3)];
            f32x4 acc2 = {0.f, 0.f, 0.f, 0.f};
            acc2 = MFMA(a0, b0, acc2, 0, 0, 0);
            acc2 = MFMA(a1, b1, acc2, 0, 0, 0);
            int col = wv * 16 + arow;
            if (col < 24) {
                #pragma unroll
                for (int rg = 0; rg < 4; ++rg)
                    Abf[p][crow0 + rg][col] = f2bf(acc2[rg] + m2bias);
            }
        }
        HPART(p, 9, 11);
        __syncthreads();

        // ---- P3: gate-part ks0 + epilogue/cell -> h(ts) into Abf[p^1] ----
        {
            {
                const unsigned short* bp = bwave;
                bf16x8 aA = *(const bf16x8*)&Abf[p][arow][akg * 8];
                bf16x8 bb[TPW];
                #pragma unroll
                for (int i = 0; i < TPW; ++i)
                    bb[i] = *(const bf16x8*)(bp + i * 512);
                #pragma unroll
                for (int i = 0; i < TPW; ++i)
                    acc[i] = MFMA(aA, bb[i], acc[i], 0, 0, 0);
            }

            if (t < RPB * NFEAT && ts + 1 < TT)
                xreg = x[((size_t)(row0 + rA) * TT + (ts + 1)) * NFEAT + eA];

            #pragma unroll
            for (int i = 0; i < TPW; ++i) {
                float bzv = BzS[(wv + 8 * i) * 16 + arow];
                float a0 = acc[i][0] + bzv;
                float a1 = acc[i][1] + bzv;
                float a2 = acc[i][2] + bzv;
                float a3 = acc[i][3] + bzv;
                acc[i] = (f32x4){0.f, 0.f, 0.f, 0.f};   // re-zero for hpart(ts+1)
                float x0 = __shfl_xor(a0, 1), x1 = __shfl_xor(a1, 1);
                float x2 = __shfl_xor(a2, 1), x3 = __shfl_xor(a3, 1);
                const bool mo = (lane & 1);
                float b0 = mo ? x1 : a0, b1 = mo ? a1 : x0;
                float b2 = mo ? x3 : a2, b3 = mo ? a3 : x2;
                float y0 = __shfl_xor(b0, 2), y1 = __shfl_xor(b1, 2);
                float y2 = __shfl_xor(b2, 2), y3 = __shfl_xor(b3, 2);
                const bool m2 = (lane & 2);
                float zi = m2 ? y2 : b0, zf = m2 ? y3 : b1;
                float zc = m2 ? b2 : y0, zo = m2 ? b3 : y1;
                if (wv + 8 * i < 75) {
                    float ig = fminf(fmaxf(0.2f * zi + 0.5f, 0.f), 1.f);
                    float fg = fminf(fmaxf(0.2f * zf + 0.5f, 0.f), 1.f);
                    float og = fminf(fmaxf(0.2f * zo + 0.5f, 0.f), 1.f);
                    float cn = fg * creg[i] + ig * ftanh(zc);
                    creg[i] = cn;
                    float hn = og * ftanh(cn);
                    Abf[p ^ 1][crow0 + q4][32 + (wv + 8 * i) * 4 + du] = f2bf(hn);
                }
            }
        }
        __syncthreads();

        // ---- P4: heads (wv<2, ks1-10) || hpart(ts+1) ks1-3 ----
        if (wv < 2) {
            f32x4 acc3 = {0.f, 0.f, 0.f, 0.f};
            #pragma unroll
            for (int ks = 1; ks < NKS; ++ks) {
                bf16x8 a = *(const bf16x8*)&Abf[p ^ 1][arow][ks * 32 + akg * 8];
                bf16x8 b = *(const bf16x8*)&SW[SWH + (wv * NKS + ks) * 512 + (lane << 3)];
                acc3 = MFMA(a, b, acc3, 0, 0, 0);
            }
            int col = wv * 16 + arow;
            if (col < 24) {
                #pragma unroll
                for (int rg = 0; rg < 4; ++rg)
                    Sc[crow0 + rg][col] = acc3[rg] + hbias;
            }
        }
        HPART(p ^ 1, 1, 4);
        __syncthreads();

        // ---- P5: softmax/out/Gbf(ts+1) || hpart(ts+1) ks4-5 ----
        if (t < RPB * NFEAT) {
            float v;
            if (eA < 8) {
                float mx = Sc[rA][0];
                #pragma unroll
                for (int m = 1; m < 8; ++m) mx = fmaxf(mx, Sc[rA][m]);
                float sum = 0.f;
                #pragma unroll
                for (int m = 0; m < 8; ++m)
                    sum += __builtin_amdgcn_exp2f((Sc[rA][m] - mx) * 1.4426950408889634f);
                v = __builtin_amdgcn_exp2f((Sc[rA][eA] - mx) * 1.4426950408889634f) / sum;
            } else if (eA < 16) {
                v = Sc[rA][eA];
            } else if (eA < 24) {
                float s = Sc[rA][eA];
                v = (s > 0.f) ? (1.f + s) : __builtin_amdgcn_exp2f(s * 1.4426950408889634f);
            } else {
                v = combreg;
            }
            out[((size_t)(row0 + rA) * TT + ts) * NFEAT + eA] = v;
            if (eA < 24) {
                Gbf[rA][eA]      = f2bf(xreg);
                Gbf[rA][25 + eA] = f2bf(v);
            } else {
                float comb = xreg + combreg;
                float denom = fmaxf(comb, 1e-8f);
                Gbf[rA][24] = f2bf(xreg / denom);
                Gbf[rA][49] = f2bf(combreg / denom);
                Abf[p ^ 1][rA][24] = f2bf(comb);
                combreg = comb;
            }
        }
        HPART(p ^ 1, 4, 6);
        __syncthreads();
    }
}

extern "C" void kernel_launch(void* const* d_in, const int* in_sizes, int n_in,
                              void* d_out, int out_size, void* d_ws, size_t ws_size,
                              hipStream_t stream) {
    const float* x   = (const float*)d_in[0];
    const float* wk  = (const float*)d_in[1];
    const float* wr  = (const float*)d_in[2];
    const float* bz  = (const float*)d_in[3];
    const float* w1  = (const float*)d_in[4];
    const float* b1  = (const float*)d_in[5];
    const float* w2  = (const float*)d_in[6];
    const float* b2  = (const float*)d_in[7];
    const float* wa  = (const float*)d_in[8];
    const float* ba  = (const float*)d_in[9];
    const float* wm  = (const float*)d_in[10];
    const float* bm  = (const float*)d_in[11];
    const float* wsg = (const float*)d_in[12];
    const float* bs  = (const float*)d_in[13];
    float* out = (float*)d_out;
    unsigned short* wf = (unsigned short*)d_ws;

    conv_big<<<(SZ_B + 255) / 256, 256, 0, stream>>>(wk, wr, wf);
    conv_gen<<<(SZ_M1 + 255) / 256, 256, 0, stream>>>(w1, wf + OFF_M1, 50, 50, 2, SZ_M1);
    conv_gen<<<(SZ_M2 + 255) / 256, 256, 0, stream>>>(w2, wf + OFF_M2, 50, 24, 2, SZ_M2);
    conv_heads<<<(SZ_H + 255) / 256, 256, 0, stream>>>(wa, wm, wsg, wf);
    dilstm<<<NBLK, NT, 0, stream>>>(x, wf, bz, b1, b2, ba, bm, bs, out);
}

// Round 12
// 4814.534 us; speedup vs baseline: 1.2850x; 1.2850x over previous
//
#include <hip/hip_runtime.h>
#include <math.h>

#define BB 2048
#define TT 512
#define NFEAT 25
#define UNITS 300
#define RPB 16
#define NBLK (BB/RPB)    // 128
#define NT 512
#define NKS 11           // ks0 = gates (bf16), ks1-10 = h (fp8)
#define TPW 10           // tiles per wave (80 tiles / 8 waves)
#define AROW 360         // Abf row stride (shorts); cols: 0-23 g, 24 comb, 32..331 h
#define F8ROW 352        // Af8 row stride (bytes); h at 32..331
#define GROW 72

#define OFF_B0 0                     // bf16 ks0 B: [wave][tile][512] shorts
#define SZ_B0  (8*TPW*512)           // 40960
#define OFF_M1 (OFF_B0 + SZ_B0)
#define SZ_M1  (4*2*512)
#define OFF_M2 (OFF_M1 + SZ_M1)
#define SZ_M2  (2*2*512)
#define OFF_H  (OFF_M2 + SZ_M2)
#define SZ_H   (2*NKS*512)
#define OFF_F8 (OFF_H + SZ_H)        // short offset where fp8 byte region begins
#define SZ_F8B (8*100*512)           // 409600 bytes: [wave][ks1-10][tile][512] bytes
#define SW_SZ  (SZ_M1 + SZ_M2 + SZ_H)
#define SWM1   0
#define SWM2   (SZ_M1)
#define SWH    (SZ_M1 + SZ_M2)

typedef __attribute__((ext_vector_type(4))) float f32x4;
typedef __attribute__((ext_vector_type(8))) short bf16x8;

static __device__ __forceinline__ unsigned short f2bf(float f) {
    union { float f; unsigned u; } x; x.f = f;
    unsigned r = (x.u + 0x7fffu + ((x.u >> 16) & 1u)) >> 16;
    return (unsigned short)r;
}
static __device__ __forceinline__ unsigned char f2f8(float f) {
    return (unsigned char)(__builtin_amdgcn_cvt_pk_fp8_f32(f, 0.f, 0, false) & 0xff);
}
static __device__ __forceinline__ float ftanh(float v) {
    float e = __builtin_amdgcn_exp2f(v * 2.8853900817779268f);
    return 1.f - 2.f * __builtin_amdgcn_rcpf(e + 1.f);
}

// gate-interleaved z columns: col' = 4*u + gate  (oc = gate*300 + u)
static __device__ __forceinline__ int zcol(int c) { return (c & 3) * 300 + (c >> 2); }

// ks0 bf16 B: [wave][tile][512]; k = kg*8+j in 0..31 (wk rows 0..24, rest 0)
__global__ __launch_bounds__(256) void conv_b0(
    const float* __restrict__ wk, unsigned short* __restrict__ dst)
{
    int idx = blockIdx.x * 256 + threadIdx.x;
    if (idx >= SZ_B0) return;
    int j = idx & 7, n = (idx >> 3) & 15, kg = (idx >> 7) & 3, q = idx >> 9;
    int i = q % TPW, w = q / TPW;
    int k = kg * 8 + j, c = (w + 8 * i) * 16 + n;
    float v = (k < 25 && c < 1200) ? wk[k * 1200 + zcol(c)] : 0.f;
    dst[OFF_B0 + idx] = f2bf(v);
}

// fp8 h-part B: [wave][ks1..10][tile][512] bytes; k = ks*32+kg*8+j, u = k-32
__global__ __launch_bounds__(256) void conv_b8(
    const float* __restrict__ wr, unsigned char* __restrict__ dst8)
{
    int idx = blockIdx.x * 256 + threadIdx.x;
    if (idx >= SZ_F8B) return;
    int j = idx & 7, n = (idx >> 3) & 15, kg = (idx >> 7) & 3, q = idx >> 9;
    int i = q % TPW, ks1 = (q / TPW) % 10, w = q / 100;
    int k = (ks1 + 1) * 32 + kg * 8 + j, c = (w + 8 * i) * 16 + n;
    float v = (k >= 32 && k < 332 && c < 1200) ? wr[(k - 32) * 1200 + zcol(c)] : 0.f;
    dst8[idx] = f2f8(v);
}

__global__ __launch_bounds__(256) void conv_gen(
    const float* __restrict__ W, unsigned short* __restrict__ dst,
    int K, int N, int nks, int total)
{
    int idx = blockIdx.x * 256 + threadIdx.x;
    if (idx >= total) return;
    int j = idx & 7, n = (idx >> 3) & 15, kg = (idx >> 7) & 3, qq = idx >> 9;
    int ks = qq % nks, nt = qq / nks;
    int k = ks * 32 + kg * 8 + j, col = nt * 16 + n;
    float v = (k < K && col < N) ? W[k * N + col] : 0.f;
    dst[idx] = f2bf(v);
}

// heads B: K'=352, h at k=32..331 (u=k-32); ks0 all zero (skipped)
__global__ __launch_bounds__(256) void conv_heads(
    const float* __restrict__ wa, const float* __restrict__ wm,
    const float* __restrict__ wsg, unsigned short* __restrict__ dst)
{
    int idx = blockIdx.x * 256 + threadIdx.x;
    if (idx >= SZ_H) return;
    int j = idx & 7, n = (idx >> 3) & 15, kg = (idx >> 7) & 3, qq = idx >> 9;
    int ks = qq % NKS, nt = qq / NKS;
    int k = ks * 32 + kg * 8 + j, col = nt * 16 + n;
    float v = 0.f;
    if (k >= 32 && k < 332 && col < 24) {
        int u = k - 32, h = col >> 3, m = col & 7;
        const float* W = (h == 0) ? wa : (h == 1) ? wm : wsg;
        v = W[u * 8 + m];
    }
    dst[OFF_H + idx] = f2bf(v);
}

#define MFMA   __builtin_amdgcn_mfma_f32_16x16x32_bf16
#define MFMA8  __builtin_amdgcn_mfma_f32_16x16x32_fp8_fp8

__global__ __launch_bounds__(NT, 2)
void dilstm(
    const float* __restrict__ x,
    const unsigned short* __restrict__ wf,
    const float* __restrict__ bz,
    const float* __restrict__ b1v,
    const float* __restrict__ b2v,
    const float* __restrict__ ba,
    const float* __restrict__ bm,
    const float* __restrict__ bs,
    float* __restrict__ out)
{
    __shared__ unsigned short Abf[2][RPB][AROW];           // bf16 A: gates 0-24, h 32-331 (heads)
    __shared__ __attribute__((aligned(16))) unsigned char Af8[2][RPB][F8ROW]; // fp8 h
    __shared__ unsigned short Gbf[RPB][GROW];
    __shared__ unsigned short G1b[RPB][GROW];
    __shared__ float Sc[RPB][24];
    __shared__ float BzS[1280];
    __shared__ unsigned short SW[SW_SZ];

    const int t = threadIdx.x;
    const int lane = t & 63, wv = t >> 6;
    const int arow = lane & 15, akg = lane >> 4;
    const int crow0 = akg * 4;
    const int q4 = lane & 3, du = (lane >> 2) & 3;
    const int row0 = blockIdx.x * RPB;

    for (int i = t; i < 2 * RPB * AROW; i += NT) ((unsigned short*)Abf)[i] = 0;
    for (int i = t; i < 2 * RPB * F8ROW; i += NT) ((unsigned char*)Af8)[i] = 0;
    for (int i = t; i < RPB * GROW; i += NT) { ((unsigned short*)Gbf)[i] = 0; ((unsigned short*)G1b)[i] = 0; }
    for (int i = t; i < SW_SZ; i += NT) SW[i] = wf[OFF_M1 + i];
    for (int i = t; i < 1280; i += NT)
        BzS[i] = (i < 1200) ? bz[zcol(i)] : 0.f;

    float m1bias = 0.f, m2bias = 0.f, hbias = 0.f;
    {
        int c1 = wv * 16 + arow;
        if (wv < 4 && c1 < 50) m1bias = b1v[c1];
        if (wv < 2 && c1 < 24) {
            m2bias = b2v[c1];
            hbias = (c1 < 8) ? ba[c1] : (c1 < 16) ? bm[c1 - 8] : bs[c1 - 16];
        }
    }

    float creg[TPW];
    #pragma unroll
    for (int i = 0; i < TPW; ++i) creg[i] = 0.f;

    const unsigned short* bw0 = wf + OFF_B0 + wv * (TPW * 512) + (lane << 3);
    const unsigned char*  bw8 = (const unsigned char*)(wf + OFF_F8) + (size_t)wv * (100 * 512) + (lane << 3);

    const int rA = t / 25, eA = t - (t / 25) * 25;
    float combreg = 0.f, xreg = 0.f;
    if (t < RPB * NFEAT) xreg = x[((size_t)(row0 + rA) * TT) * NFEAT + eA];
    __syncthreads();

    // initial gate-input build (prev = 0)
    if (t < RPB * NFEAT) {
        if (eA < 24) {
            Gbf[rA][eA] = f2bf(xreg);
        } else {
            float comb = xreg;
            combreg = comb;
            float denom = fmaxf(comb, 1e-8f);
            Gbf[rA][24] = f2bf(xreg / denom);
            Abf[0][rA][24] = f2bf(comb);
        }
    }
    __syncthreads();

    for (int ts = 0; ts < TT; ++ts) {
        const int p = ts & 1;

        // ---- P1: MLP1 (waves 0-3) ----
        if (wv < 4) {
            bf16x8 a0 = *(const bf16x8*)&Gbf[arow][akg * 8];
            bf16x8 a1 = *(const bf16x8*)&Gbf[arow][32 + akg * 8];
            bf16x8 b0 = *(const bf16x8*)&SW[SWM1 + (wv * 2 + 0) * 512 + (lane << 3)];
            bf16x8 b1 = *(const bf16x8*)&SW[SWM1 + (wv * 2 + 1) * 512 + (lane << 3)];
            f32x4 acc1 = {0.f, 0.f, 0.f, 0.f};
            acc1 = MFMA(a0, b0, acc1, 0, 0, 0);
            acc1 = MFMA(a1, b1, acc1, 0, 0, 0);
            int col = wv * 16 + arow;
            if (col < 50) {
                #pragma unroll
                for (int rg = 0; rg < 4; ++rg)
                    G1b[crow0 + rg][col] = f2bf(fmaxf(acc1[rg] + m1bias, 0.f));
            }
        }
        __syncthreads();

        // ---- P2: MLP2 (waves 0-1) -> Abf[p][.][0..23] ----
        if (wv < 2) {
            bf16x8 a0 = *(const bf16x8*)&G1b[arow][akg * 8];
            bf16x8 a1 = *(const bf16x8*)&G1b[arow][32 + akg * 8];
            bf16x8 b0 = *(const bf16x8*)&SW[SWM2 + (wv * 2 + 0) * 512 + (lane << 3)];
            bf16x8 b1 = *(const bf16x8*)&SW[SWM2 + (wv * 2 + 1) * 512 + (lane << 3)];
            f32x4 acc2 = {0.f, 0.f, 0.f, 0.f};
            acc2 = MFMA(a0, b0, acc2, 0, 0, 0);
            acc2 = MFMA(a1, b1, acc2, 0, 0, 0);
            int col = wv * 16 + arow;
            if (col < 24) {
                #pragma unroll
                for (int rg = 0; rg < 4; ++rg)
                    Abf[p][crow0 + rg][col] = f2bf(acc2[rg] + m2bias);
            }
        }
        __syncthreads();

        // ---- P3: big GEMM (ks0 bf16 + ks1-10 fp8) + fused cell ----
        {
            f32x4 acc[TPW];
            #pragma unroll
            for (int i = 0; i < TPW; ++i) acc[i] = (f32x4){0.f, 0.f, 0.f, 0.f};

            // ks0: gates, bf16
            {
                bf16x8 aA = *(const bf16x8*)&Abf[p][arow][akg * 8];
                bf16x8 bb[TPW];
                #pragma unroll
                for (int i = 0; i < TPW; ++i)
                    bb[i] = *(const bf16x8*)(bw0 + i * 512);
                #pragma unroll
                for (int i = 0; i < TPW; ++i)
                    acc[i] = MFMA(aA, bb[i], acc[i], 0, 0, 0);
            }
            // ks1-10: h, fp8; sequential B stream, one running pointer
            {
                const unsigned char* bp8 = bw8;
                const unsigned char* af8p = &Af8[p][0][0];
                #pragma unroll 1
                for (int ks = 1; ks < NKS; ++ks) {
                    long long a8 = *(const long long*)(af8p + arow * F8ROW + ks * 32 + akg * 8);
                    long long b8[TPW];
                    #pragma unroll
                    for (int i = 0; i < TPW; ++i)
                        b8[i] = *(const long long*)(bp8 + i * 512);
                    #pragma unroll
                    for (int i = 0; i < TPW; ++i)
                        acc[i] = MFMA8(a8, b8[i], acc[i], 0, 0, 0);
                    bp8 += TPW * 512;
                }
            }

            if (t < RPB * NFEAT && ts + 1 < TT)
                xreg = x[((size_t)(row0 + rA) * TT + (ts + 1)) * NFEAT + eA];

            // per-tile: bias, 4-lane 4x4 transpose, cell, h -> Abf/Af8[p^1]
            #pragma unroll
            for (int i = 0; i < TPW; ++i) {
                float bzv = BzS[(wv + 8 * i) * 16 + arow];
                float a0 = acc[i][0] + bzv;
                float a1 = acc[i][1] + bzv;
                float a2 = acc[i][2] + bzv;
                float a3 = acc[i][3] + bzv;
                float x0 = __shfl_xor(a0, 1), x1 = __shfl_xor(a1, 1);
                float x2 = __shfl_xor(a2, 1), x3 = __shfl_xor(a3, 1);
                const bool mo = (lane & 1);
                float b0 = mo ? x1 : a0, b1 = mo ? a1 : x0;
                float b2 = mo ? x3 : a2, b3 = mo ? a3 : x2;
                float y0 = __shfl_xor(b0, 2), y1 = __shfl_xor(b1, 2);
                float y2 = __shfl_xor(b2, 2), y3 = __shfl_xor(b3, 2);
                const bool m2 = (lane & 2);
                float zi = m2 ? y2 : b0, zf = m2 ? y3 : b1;
                float zc = m2 ? b2 : y0, zo = m2 ? b3 : y1;
                if (wv + 8 * i < 75) {
                    float ig = fminf(fmaxf(0.2f * zi + 0.5f, 0.f), 1.f);
                    float fg = fminf(fmaxf(0.2f * zf + 0.5f, 0.f), 1.f);
                    float og = fminf(fmaxf(0.2f * zo + 0.5f, 0.f), 1.f);
                    float cn = fg * creg[i] + ig * ftanh(zc);
                    creg[i] = cn;
                    float hn = og * ftanh(cn);
                    int hc = 32 + (wv + 8 * i) * 4 + du;
                    Abf[p ^ 1][crow0 + q4][hc] = f2bf(hn);
                    Af8[p ^ 1][crow0 + q4][hc] = f2f8(hn);
                }
            }
        }
        __syncthreads();

        // ---- P4: heads (waves 0-1), ks1-10 bf16 ----
        if (wv < 2) {
            f32x4 acc3 = {0.f, 0.f, 0.f, 0.f};
            #pragma unroll
            for (int ks = 1; ks < NKS; ++ks) {
                bf16x8 a = *(const bf16x8*)&Abf[p ^ 1][arow][ks * 32 + akg * 8];
                bf16x8 b = *(const bf16x8*)&SW[SWH + (wv * NKS + ks) * 512 + (lane << 3)];
                acc3 = MFMA(a, b, acc3, 0, 0, 0);
            }
            int col = wv * 16 + arow;
            if (col < 24) {
                #pragma unroll
                for (int rg = 0; rg < 4; ++rg)
                    Sc[crow0 + rg][col] = acc3[rg] + hbias;
            }
        }
        __syncthreads();

        // ---- P5: softmax/nnelu + out + next-step gate input ----
        if (t < RPB * NFEAT) {
            float v;
            if (eA < 8) {
                float mx = Sc[rA][0];
                #pragma unroll
                for (int m = 1; m < 8; ++m) mx = fmaxf(mx, Sc[rA][m]);
                float sum = 0.f;
                #pragma unroll
                for (int m = 0; m < 8; ++m)
                    sum += __builtin_amdgcn_exp2f((Sc[rA][m] - mx) * 1.4426950408889634f);
                v = __builtin_amdgcn_exp2f((Sc[rA][eA] - mx) * 1.4426950408889634f) / sum;
            } else if (eA < 16) {
                v = Sc[rA][eA];
            } else if (eA < 24) {
                float s = Sc[rA][eA];
                v = (s > 0.f) ? (1.f + s) : __builtin_amdgcn_exp2f(s * 1.4426950408889634f);
            } else {
                v = combreg;
            }
            out[((size_t)(row0 + rA) * TT + ts) * NFEAT + eA] = v;
            if (eA < 24) {
                Gbf[rA][eA]      = f2bf(xreg);
                Gbf[rA][25 + eA] = f2bf(v);
            } else {
                float comb = xreg + combreg;
                float denom = fmaxf(comb, 1e-8f);
                Gbf[rA][24] = f2bf(xreg / denom);
                Gbf[rA][49] = f2bf(combreg / denom);
                Abf[p ^ 1][rA][24] = f2bf(comb);
                combreg = comb;
            }
        }
        __syncthreads();
    }
}

extern "C" void kernel_launch(void* const* d_in, const int* in_sizes, int n_in,
                              void* d_out, int out_size, void* d_ws, size_t ws_size,
                              hipStream_t stream) {
    const float* x   = (const float*)d_in[0];
    const float* wk  = (const float*)d_in[1];
    const float* wr  = (const float*)d_in[2];
    const float* bz  = (const float*)d_in[3];
    const float* w1  = (const float*)d_in[4];
    const float* b1  = (const float*)d_in[5];
    const float* w2  = (const float*)d_in[6];
    const float* b2  = (const float*)d_in[7];
    const float* wa  = (const float*)d_in[8];
    const float* ba  = (const float*)d_in[9];
    const float* wm  = (const float*)d_in[10];
    const float* bm  = (const float*)d_in[11];
    const float* wsg = (const float*)d_in[12];
    const float* bs  = (const float*)d_in[13];
    float* out = (float*)d_out;
    unsigned short* wf = (unsigned short*)d_ws;
    unsigned char*  wf8 = (unsigned char*)(wf + OFF_F8);

    conv_b0<<<(SZ_B0 + 255) / 256, 256, 0, stream>>>(wk, wf);
    conv_b8<<<(SZ_F8B + 255) / 256, 256, 0, stream>>>(wr, wf8);
    conv_gen<<<(SZ_M1 + 255) / 256, 256, 0, stream>>>(w1, wf + OFF_M1, 50, 50, 2, SZ_M1);
    conv_gen<<<(SZ_M2 + 255) / 256, 256, 0, stream>>>(w2, wf + OFF_M2, 50, 24, 2, SZ_M2);
    conv_heads<<<(SZ_H + 255) / 256, 256, 0, stream>>>(wa, wm, wsg, wf);
    dilstm<<<NBLK, NT, 0, stream>>>(x, wf, bz, b1, b2, ba, bm, bs, out);
}

// Round 13
// 3936.011 us; speedup vs baseline: 1.5718x; 1.2232x over previous
//
#include <hip/hip_runtime.h>
#include <math.h>

#define BB 2048
#define TT 512
#define NFEAT 25
#define UNITS 300
#define RPB 16
#define NBLK (BB/RPB)    // 128
#define NT 512
#define NKS 11           // ks0 = gates (bf16), ks1-10 = h (fp8)
#define TPW 10           // tiles per wave (80 tiles / 8 waves)
#define AROW 360         // Abf row stride (shorts); cols: 0-23 g, 24 comb, 32..331 h
#define F8ROW 352        // Af8 row stride (bytes); h at 32..331
#define GROW 72

#define OFF_B0 0                     // bf16 ks0 B: [wave][tile][512] shorts
#define SZ_B0  (8*TPW*512)           // 40960
#define OFF_M1 (OFF_B0 + SZ_B0)
#define SZ_M1  (4*2*512)
#define OFF_M2 (OFF_M1 + SZ_M1)
#define SZ_M2  (2*2*512)
#define OFF_H  (OFF_M2 + SZ_M2)
#define SZ_H   (2*NKS*512)
#define OFF_F8 (OFF_H + SZ_H)        // short offset where fp8 byte region begins
#define SZ_F8B (8*100*512)           // 409600 bytes: [wave][ks1-10][tile][512] bytes
#define SW_SZ  (SZ_M1 + SZ_M2 + SZ_H)
#define SWM1   0
#define SWM2   (SZ_M1)
#define SWH    (SZ_M1 + SZ_M2)

typedef __attribute__((ext_vector_type(4))) float f32x4;
typedef __attribute__((ext_vector_type(8))) short bf16x8;

static __device__ __forceinline__ unsigned short f2bf(float f) {
    union { float f; unsigned u; } x; x.f = f;
    unsigned r = (x.u + 0x7fffu + ((x.u >> 16) & 1u)) >> 16;
    return (unsigned short)r;
}
static __device__ __forceinline__ unsigned char f2f8(float f) {
    return (unsigned char)(__builtin_amdgcn_cvt_pk_fp8_f32(f, 0.f, 0, false) & 0xff);
}
static __device__ __forceinline__ float ftanh(float v) {
    float e = __builtin_amdgcn_exp2f(v * 2.8853900817779268f);
    return 1.f - 2.f * __builtin_amdgcn_rcpf(e + 1.f);
}

// gate-interleaved z columns: col' = 4*u + gate  (oc = gate*300 + u)
static __device__ __forceinline__ int zcol(int c) { return (c & 3) * 300 + (c >> 2); }

// ks0 bf16 B: [wave][tile][512]; k = kg*8+j in 0..31 (wk rows 0..24, rest 0)
__global__ __launch_bounds__(256) void conv_b0(
    const float* __restrict__ wk, unsigned short* __restrict__ dst)
{
    int idx = blockIdx.x * 256 + threadIdx.x;
    if (idx >= SZ_B0) return;
    int j = idx & 7, n = (idx >> 3) & 15, kg = (idx >> 7) & 3, q = idx >> 9;
    int i = q % TPW, w = q / TPW;
    int k = kg * 8 + j, c = (w + 8 * i) * 16 + n;
    float v = (k < 25 && c < 1200) ? wk[k * 1200 + zcol(c)] : 0.f;
    dst[OFF_B0 + idx] = f2bf(v);
}

// fp8 h-part B: [wave][ks1..10][tile][512] bytes; k = ks*32+kg*8+j, u = k-32
__global__ __launch_bounds__(256) void conv_b8(
    const float* __restrict__ wr, unsigned char* __restrict__ dst8)
{
    int idx = blockIdx.x * 256 + threadIdx.x;
    if (idx >= SZ_F8B) return;
    int j = idx & 7, n = (idx >> 3) & 15, kg = (idx >> 7) & 3, q = idx >> 9;
    int i = q % TPW, ks1 = (q / TPW) % 10, w = q / 100;
    int k = (ks1 + 1) * 32 + kg * 8 + j, c = (w + 8 * i) * 16 + n;
    float v = (k >= 32 && k < 332 && c < 1200) ? wr[(k - 32) * 1200 + zcol(c)] : 0.f;
    dst8[idx] = f2f8(v);
}

__global__ __launch_bounds__(256) void conv_gen(
    const float* __restrict__ W, unsigned short* __restrict__ dst,
    int K, int N, int nks, int total)
{
    int idx = blockIdx.x * 256 + threadIdx.x;
    if (idx >= total) return;
    int j = idx & 7, n = (idx >> 3) & 15, kg = (idx >> 7) & 3, qq = idx >> 9;
    int ks = qq % nks, nt = qq / nks;
    int k = ks * 32 + kg * 8 + j, col = nt * 16 + n;
    float v = (k < K && col < N) ? W[k * N + col] : 0.f;
    dst[idx] = f2bf(v);
}

// heads B: K'=352, h at k=32..331 (u=k-32); ks0 all zero (skipped)
__global__ __launch_bounds__(256) void conv_heads(
    const float* __restrict__ wa, const float* __restrict__ wm,
    const float* __restrict__ wsg, unsigned short* __restrict__ dst)
{
    int idx = blockIdx.x * 256 + threadIdx.x;
    if (idx >= SZ_H) return;
    int j = idx & 7, n = (idx >> 3) & 15, kg = (idx >> 7) & 3, qq = idx >> 9;
    int ks = qq % NKS, nt = qq / NKS;
    int k = ks * 32 + kg * 8 + j, col = nt * 16 + n;
    float v = 0.f;
    if (k >= 32 && k < 332 && col < 24) {
        int u = k - 32, h = col >> 3, m = col & 7;
        const float* W = (h == 0) ? wa : (h == 1) ? wm : wsg;
        v = W[u * 8 + m];
    }
    dst[OFF_H + idx] = f2bf(v);
}

#define MFMA   __builtin_amdgcn_mfma_f32_16x16x32_bf16
#define MFMA8  __builtin_amdgcn_mfma_f32_16x16x32_fp8_fp8

__global__ __launch_bounds__(NT, 2)
void dilstm(
    const float* __restrict__ x,
    const unsigned short* __restrict__ wf,
    const float* __restrict__ bz,
    const float* __restrict__ b1v,
    const float* __restrict__ b2v,
    const float* __restrict__ ba,
    const float* __restrict__ bm,
    const float* __restrict__ bs,
    float* __restrict__ out)
{
    __shared__ unsigned short Abf[2][RPB][AROW];           // bf16 A: gates 0-24, h 32-331
    __shared__ __attribute__((aligned(16))) unsigned char Af8[2][RPB][F8ROW]; // fp8 h
    __shared__ unsigned short Gbf[RPB][GROW];
    __shared__ unsigned short G1b[RPB][GROW];
    __shared__ float Sc[RPB][24];
    __shared__ float BzS[1280];
    __shared__ float Zw[8][2][16][20];                     // per-wave z staging (dbuf)
    __shared__ unsigned short SW[SW_SZ];

    const int t = threadIdx.x;
    const int lane = t & 63, wv = t >> 6;
    const int arow = lane & 15, akg = lane >> 4;
    const int crow0 = akg * 4;
    const int u_l = lane & 3, rr = lane >> 2;
    const int row0 = blockIdx.x * RPB;

    for (int i = t; i < 2 * RPB * AROW; i += NT) ((unsigned short*)Abf)[i] = 0;
    for (int i = t; i < 2 * RPB * F8ROW; i += NT) ((unsigned char*)Af8)[i] = 0;
    for (int i = t; i < RPB * GROW; i += NT) { ((unsigned short*)Gbf)[i] = 0; ((unsigned short*)G1b)[i] = 0; }
    for (int i = t; i < SW_SZ; i += NT) SW[i] = wf[OFF_M1 + i];
    for (int i = t; i < 1280; i += NT)
        BzS[i] = (i < 1200) ? bz[zcol(i)] : 0.f;

    float m1bias = 0.f, m2bias = 0.f, hbias = 0.f;
    {
        int c1 = wv * 16 + arow;
        if (wv < 4 && c1 < 50) m1bias = b1v[c1];
        if (wv < 2 && c1 < 24) {
            m2bias = b2v[c1];
            hbias = (c1 < 8) ? ba[c1] : (c1 < 16) ? bm[c1 - 8] : bs[c1 - 16];
        }
    }

    float creg[TPW];
    #pragma unroll
    for (int i = 0; i < TPW; ++i) creg[i] = 0.f;

    const unsigned short* bw0 = wf + OFF_B0 + wv * (TPW * 512) + (lane << 3);
    const unsigned char*  bw8 = (const unsigned char*)(wf + OFF_F8) + (size_t)wv * (100 * 512) + (lane << 3);

    const int rA = t / 25, eA = t - (t / 25) * 25;
    float combreg = 0.f, xreg = 0.f;
    if (t < RPB * NFEAT) xreg = x[((size_t)(row0 + rA) * TT) * NFEAT + eA];
    __syncthreads();

    // initial gate-input build (prev = 0)
    if (t < RPB * NFEAT) {
        if (eA < 24) {
            Gbf[rA][eA] = f2bf(xreg);
        } else {
            float comb = xreg;
            combreg = comb;
            float denom = fmaxf(comb, 1e-8f);
            Gbf[rA][24] = f2bf(xreg / denom);
            Abf[0][rA][24] = f2bf(comb);
        }
    }
    __syncthreads();

    for (int ts = 0; ts < TT; ++ts) {
        const int p = ts & 1;

        // ---- P1: MLP1 (waves 0-3) ----
        if (wv < 4) {
            bf16x8 a0 = *(const bf16x8*)&Gbf[arow][akg * 8];
            bf16x8 a1 = *(const bf16x8*)&Gbf[arow][32 + akg * 8];
            bf16x8 b0 = *(const bf16x8*)&SW[SWM1 + (wv * 2 + 0) * 512 + (lane << 3)];
            bf16x8 b1 = *(const bf16x8*)&SW[SWM1 + (wv * 2 + 1) * 512 + (lane << 3)];
            f32x4 acc1 = {0.f, 0.f, 0.f, 0.f};
            acc1 = MFMA(a0, b0, acc1, 0, 0, 0);
            acc1 = MFMA(a1, b1, acc1, 0, 0, 0);
            int col = wv * 16 + arow;
            if (col < 50) {
                #pragma unroll
                for (int rg = 0; rg < 4; ++rg)
                    G1b[crow0 + rg][col] = f2bf(fmaxf(acc1[rg] + m1bias, 0.f));
            }
        }
        __syncthreads();

        // ---- P2: MLP2 (waves 0-1) -> Abf[p][.][0..23] ----
        if (wv < 2) {
            bf16x8 a0 = *(const bf16x8*)&G1b[arow][akg * 8];
            bf16x8 a1 = *(const bf16x8*)&G1b[arow][32 + akg * 8];
            bf16x8 b0 = *(const bf16x8*)&SW[SWM2 + (wv * 2 + 0) * 512 + (lane << 3)];
            bf16x8 b1 = *(const bf16x8*)&SW[SWM2 + (wv * 2 + 1) * 512 + (lane << 3)];
            f32x4 acc2 = {0.f, 0.f, 0.f, 0.f};
            acc2 = MFMA(a0, b0, acc2, 0, 0, 0);
            acc2 = MFMA(a1, b1, acc2, 0, 0, 0);
            int col = wv * 16 + arow;
            if (col < 24) {
                #pragma unroll
                for (int rg = 0; rg < 4; ++rg)
                    Abf[p][crow0 + rg][col] = f2bf(acc2[rg] + m2bias);
            }
        }
        __syncthreads();

        // ---- P3: pipelined GEMM (ks0 bf16 + ks1-10 fp8) + LDS-staged cell ----
        {
            // x prefetch first: HBM latency drains under the GEMM
            if (t < RPB * NFEAT && ts + 1 < TT)
                xreg = x[((size_t)(row0 + rA) * TT + (ts + 1)) * NFEAT + eA];

            f32x4 acc[TPW];
            #pragma unroll
            for (int i = 0; i < TPW; ++i) acc[i] = (f32x4){0.f, 0.f, 0.f, 0.f};

            // ks0: gates, bf16 (batch load -> mfma)
            {
                bf16x8 bb0[TPW];
                #pragma unroll
                for (int i = 0; i < TPW; ++i)
                    bb0[i] = *(const bf16x8*)(bw0 + i * 512);
                bf16x8 aA = *(const bf16x8*)&Abf[p][arow][akg * 8];
                #pragma unroll
                for (int i = 0; i < TPW; ++i)
                    acc[i] = MFMA(aA, bb0[i], acc[i], 0, 0, 0);
            }
            // ks1-10: fp8, software-pipelined depth 2, one running pointer
            {
                const unsigned char* af8p = &Af8[p][0][0] + arow * F8ROW + akg * 8;
                const unsigned char* bp = bw8;
                long long bbA[TPW], bbB[TPW];
                #pragma unroll
                for (int i = 0; i < TPW; ++i)
                    bbA[i] = *(const long long*)(bp + i * 512);
                #pragma unroll 1
                for (int pr = 0; pr < 5; ++pr) {
                    const int ks = 2 * pr + 1;
                    #pragma unroll
                    for (int i = 0; i < TPW; ++i)
                        bbB[i] = *(const long long*)(bp + 5120 + i * 512);
                    long long a8a = *(const long long*)(af8p + ks * 32);
                    #pragma unroll
                    for (int i = 0; i < TPW; ++i)
                        acc[i] = MFMA8(a8a, bbA[i], acc[i], 0, 0, 0);
                    if (pr < 4) {
                        #pragma unroll
                        for (int i = 0; i < TPW; ++i)
                            bbA[i] = *(const long long*)(bp + 10240 + i * 512);
                    }
                    long long a8b = *(const long long*)(af8p + ks * 32 + 32);
                    #pragma unroll
                    for (int i = 0; i < TPW; ++i)
                        acc[i] = MFMA8(a8b, bbB[i], acc[i], 0, 0, 0);
                    bp += 10240;
                }
            }

            // epilogue: per-wave LDS gate-regroup (no shuffles), double-buffered
            *(f32x4*)&Zw[wv][0][arow][crow0] = acc[0];
            #pragma unroll
            for (int i = 0; i < TPW; ++i) {
                if (i + 1 < TPW)
                    *(f32x4*)&Zw[wv][(i + 1) & 1][arow][crow0] = acc[i + 1];
                f32x4 bz4 = *(const f32x4*)&BzS[(wv + 8 * i) * 16 + 4 * u_l];
                const float* zp = &Zw[wv][i & 1][4 * u_l][rr];
                float zi = zp[0]  + bz4[0];
                float zf = zp[20] + bz4[1];
                float zc = zp[40] + bz4[2];
                float zo = zp[60] + bz4[3];
                if (wv + 8 * i < 75) {
                    float ig = fminf(fmaxf(0.2f * zi + 0.5f, 0.f), 1.f);
                    float fg = fminf(fmaxf(0.2f * zf + 0.5f, 0.f), 1.f);
                    float og = fminf(fmaxf(0.2f * zo + 0.5f, 0.f), 1.f);
                    float cn = fg * creg[i] + ig * ftanh(zc);
                    creg[i] = cn;
                    float hn = og * ftanh(cn);
                    int hc = 32 + (wv + 8 * i) * 4 + u_l;
                    Abf[p ^ 1][rr][hc] = f2bf(hn);
                    Af8[p ^ 1][rr][hc] = f2f8(hn);
                }
            }
        }
        __syncthreads();

        // ---- P4: heads (waves 0-1), ks1-10 bf16 ----
        if (wv < 2) {
            f32x4 acc3 = {0.f, 0.f, 0.f, 0.f};
            #pragma unroll
            for (int ks = 1; ks < NKS; ++ks) {
                bf16x8 a = *(const bf16x8*)&Abf[p ^ 1][arow][ks * 32 + akg * 8];
                bf16x8 b = *(const bf16x8*)&SW[SWH + (wv * NKS + ks) * 512 + (lane << 3)];
                acc3 = MFMA(a, b, acc3, 0, 0, 0);
            }
            int col = wv * 16 + arow;
            if (col < 24) {
                #pragma unroll
                for (int rg = 0; rg < 4; ++rg)
                    Sc[crow0 + rg][col] = acc3[rg] + hbias;
            }
        }
        __syncthreads();

        // ---- P5: softmax/nnelu + out + next-step gate input ----
        if (t < RPB * NFEAT) {
            float v;
            if (eA < 8) {
                float mx = Sc[rA][0];
                #pragma unroll
                for (int m = 1; m < 8; ++m) mx = fmaxf(mx, Sc[rA][m]);
                float sum = 0.f;
                #pragma unroll
                for (int m = 0; m < 8; ++m)
                    sum += __builtin_amdgcn_exp2f((Sc[rA][m] - mx) * 1.4426950408889634f);
                v = __builtin_amdgcn_exp2f((Sc[rA][eA] - mx) * 1.4426950408889634f) / sum;
            } else if (eA < 16) {
                v = Sc[rA][eA];
            } else if (eA < 24) {
                float s = Sc[rA][eA];
                v = (s > 0.f) ? (1.f + s) : __builtin_amdgcn_exp2f(s * 1.4426950408889634f);
            } else {
                v = combreg;
            }
            out[((size_t)(row0 + rA) * TT + ts) * NFEAT + eA] = v;
            if (eA < 24) {
                Gbf[rA][eA]      = f2bf(xreg);
                Gbf[rA][25 + eA] = f2bf(v);
            } else {
                float comb = xreg + combreg;
                float denom = fmaxf(comb, 1e-8f);
                Gbf[rA][24] = f2bf(xreg / denom);
                Gbf[rA][49] = f2bf(combreg / denom);
                Abf[p ^ 1][rA][24] = f2bf(comb);
                combreg = comb;
            }
        }
        __syncthreads();
    }
}

extern "C" void kernel_launch(void* const* d_in, const int* in_sizes, int n_in,
                              void* d_out, int out_size, void* d_ws, size_t ws_size,
                              hipStream_t stream) {
    const float* x   = (const float*)d_in[0];
    const float* wk  = (const float*)d_in[1];
    const float* wr  = (const float*)d_in[2];
    const float* bz  = (const float*)d_in[3];
    const float* w1  = (const float*)d_in[4];
    const float* b1  = (const float*)d_in[5];
    const float* w2  = (const float*)d_in[6];
    const float* b2  = (const float*)d_in[7];
    const float* wa  = (const float*)d_in[8];
    const float* ba  = (const float*)d_in[9];
    const float* wm  = (const float*)d_in[10];
    const float* bm  = (const float*)d_in[11];
    const float* wsg = (const float*)d_in[12];
    const float* bs  = (const float*)d_in[13];
    float* out = (float*)d_out;
    unsigned short* wf = (unsigned short*)d_ws;
    unsigned char*  wf8 = (unsigned char*)(wf + OFF_F8);

    conv_b0<<<(SZ_B0 + 255) / 256, 256, 0, stream>>>(wk, wf);
    conv_b8<<<(SZ_F8B + 255) / 256, 256, 0, stream>>>(wr, wf8);
    conv_gen<<<(SZ_M1 + 255) / 256, 256, 0, stream>>>(w1, wf + OFF_M1, 50, 50, 2, SZ_M1);
    conv_gen<<<(SZ_M2 + 255) / 256, 256, 0, stream>>>(w2, wf + OFF_M2, 50, 24, 2, SZ_M2);
    conv_heads<<<(SZ_H + 255) / 256, 256, 0, stream>>>(wa, wm, wsg, wf);
    dilstm<<<NBLK, NT, 0, stream>>>(x, wf, bz, b1, b2, ba, bm, bs, out);
}